// Round 4
// baseline (189.233 us; speedup 1.0000x reference)
//
#include <hip/hip_runtime.h>

#define CDIM 128
#define NHEADS 8
#define HD 16
#define NTOK 64
#define HW 65536          // 256*256 pixels per image
#define XSTR 136          // padded row stride (bf16 shorts) for 64x128 tiles
#define VSTR 72           // row stride (shorts) for [16][64] vt/P scratch tiles
#define SLOT 2304         // per-wave vsc slot (shorts) = max(2*64*16, 2*16*72)
#define LOG2E 1.44269504088896f

typedef short s8v __attribute__((ext_vector_type(8)));
typedef short s4v __attribute__((ext_vector_type(4)));
typedef float f4v __attribute__((ext_vector_type(4)));

static __device__ __forceinline__ short f2bf(float f) {
    unsigned u = __float_as_uint(f);
    u += 0x7FFFu + ((u >> 16) & 1u);   // RNE
    return (short)(u >> 16);
}
// packed RNE f32x2 -> bf16x2 (T12 recipe; no builtin on gfx950)
static __device__ __forceinline__ unsigned cvt2(float lo, float hi) {
    unsigned r;
    asm("v_cvt_pk_bf16_f32 %0, %1, %2" : "=v"(r) : "v"(lo), "v"(hi));
    return r;
}
static __device__ __forceinline__ uint2 pk4(float a, float b, float c, float d) {
    return make_uint2(cvt2(a, b), cvt2(c, d));
}

// ---- Prologue 1: pack qkv_w (rows 0..383) + proj_w (rows 0..127) into MFMA
// fragment order. frag f = ob*4+kc; ob 0..7 = q (pre-scaled 0.25*log2e so the
// softmax can use exp2 directly), 8..15 = k, 16..23 = v, 24..31 = proj.
// wpk[(f*64+lane)*8 + j] = W[ob*16 + (lane&15)][kc*32 + (lane>>4)*8 + j]
__global__ __launch_bounds__(256) void pack_w_kernel(
    const float* __restrict__ qkv_w, const float* __restrict__ proj_w,
    short* __restrict__ wpk)
{
    int idx = blockIdx.x * 256 + threadIdx.x;   // 0..8191
    int lane = idx & 63, kc = (idx >> 6) & 3, ob = idx >> 8;
    int row = (ob < 24) ? ob * 16 + (lane & 15) : (ob - 24) * 16 + (lane & 15);
    int col = kc * 32 + (lane >> 4) * 8;
    const float* src = ((ob < 24) ? qkv_w : proj_w) + (size_t)row * CDIM + col;
    float sc = (ob < 8) ? 0.25f * LOG2E : 1.0f;
    float4 f0 = *(const float4*)src;
    float4 f1 = *(const float4*)(src + 4);
    s8v r;
    r[0] = f2bf(f0.x * sc); r[1] = f2bf(f0.y * sc);
    r[2] = f2bf(f0.z * sc); r[3] = f2bf(f0.w * sc);
    r[4] = f2bf(f1.x * sc); r[5] = f2bf(f1.y * sc);
    r[6] = f2bf(f1.z * sc); r[7] = f2bf(f1.w * sc);
    *(s8v*)&wpk[(size_t)idx * 8] = r;
}

// ---- Prologue 2: gather rel_bias[rel_index] (scaled by log2e) into S^T
// C-fragment order: biasf[(((h*4+mq)*4+nt)*64 + lane)*4 + r] =
//   log2e * bias[h][t_q = mq*16+(lane&15)][t_k = nt*16+(lane>>4)*4+r]
__global__ __launch_bounds__(256) void pack_b_kernel(
    const float* __restrict__ rel_bias, const int* __restrict__ rel_index,
    float* __restrict__ biasf)
{
    int idx = blockIdx.x * 256 + threadIdx.x;   // 0..8191
    int lane = idx & 63, nt = (idx >> 6) & 3, mq = (idx >> 8) & 3, h = idx >> 10;
    int tq  = mq * 16 + (lane & 15);
    int tk0 = nt * 16 + (lane >> 4) * 4;
    f4v v;
    #pragma unroll
    for (int r = 0; r < 4; ++r)
        v[r] = LOG2E * rel_bias[rel_index[tq * 64 + tk0 + r] * NHEADS + h];
    *(f4v*)&biasf[(size_t)idx * 4] = v;
}

// ---- Main: one block per HORIZONTAL PAIR of 8x8 windows (8x16 px), 512
// threads = 8 waves. Waves 0-3 run window 0, waves 4-7 run window 1; wave
// quad-index w4 owns heads {w4, w4+4} of its window. Every 64B line of
// x/out is consumed/produced entirely inside one block (the two windows
// each cover 32B halves of the same lines) -> no cross-block L2 residency
// dependence. LDS = 71680 B -> 2 blocks/CU -> 4 waves/SIMD.
__global__ __launch_bounds__(512, 4) void winattn_kernel(
    const float* __restrict__ x, const float* __restrict__ qkv_b,
    const float* __restrict__ proj_b, const short* __restrict__ wpk,
    const float* __restrict__ biasf, float* __restrict__ out)
{
    // per-window xs: staged x (granule-swizzled) -> q overlay -> attn-out
    __shared__ __align__(16) short xs[2 * NTOK * XSTR];   // 34816 B
    __shared__ __align__(16) short vsc[8 * SLOT];         // 36864 B (wave-private)

    const int tid  = threadIdx.x;
    const int lane = tid & 63;
    const int wv   = tid >> 6;       // 0..7
    const int win  = wv >> 2;        // window within the pair
    const int w4   = wv & 3;         // wave quad-index within the window
    const int qd   = lane >> 4;
    const int l15  = lane & 15;
    short* myxs = &xs[win * NTOK * XSTR];
    short* myv  = &vsc[wv * SLOT];

    const int wid = blockIdx.x;      // 0..1023 (pairs)
    const int b   = wid >> 9;
    const int rem = wid & 511;
    const int wy  = rem >> 4, kx = rem & 15;
    const int h0  = wy * 8, w0 = kx * 16 + win * 8;
    const float* xb = x + (size_t)b * CDIM * HW;

    // ---------- Stage 1: stage own window into myxs (bf16, granule-swizzled)
    // Element (t, c) lives at myxs[t*XSTR + (((c>>3) ^ ((t>>2)&7))<<3) + (c&7)].
    #pragma unroll
    for (int it = 0; it < 8; ++it) {
        const int g   = it * 4 + w4;              // 0..31 group id
        const int cg  = g & 15, tqg = g >> 4;
        const int c   = cg * 8 + ((lane >> 3) & 7);
        const int tq  = tqg * 8 + (lane & 7);
        const int t0  = tq * 4;
        float4 f = *(const float4*)&xb[(size_t)c * HW + (h0 + (t0 >> 3)) * 256 + w0 + (t0 & 7)];
        const int col = ((cg ^ (tq & 7)) << 3) | (c & 7);
        myxs[(t0 + 0) * XSTR + col] = f2bf(f.x);
        myxs[(t0 + 1) * XSTR + col] = f2bf(f.y);
        myxs[(t0 + 2) * XSTR + col] = f2bf(f.z);
        myxs[(t0 + 3) * XSTR + col] = f2bf(f.w);
    }
    __syncthreads();

    // ---------- Stage 2: QKV GEMM, head-aligned per wave; order v -> k -> q --
    s8v vf[2][2];   // v B-frags for heads {w4, w4+4}
    s8v kf[2][4];   // k A-frags (loaded after q-section)
    const int kswz = (l15 >> 1) & 2;   // even-only channel-granule XOR for k scratch
    {
        // X A-frags: X[tb][kc] = x[t = tb*16+l15][c = kc*32+qd*8 .. +7]
        s8v X[4][4];
        #pragma unroll
        for (int tb = 0; tb < 4; ++tb)
            #pragma unroll
            for (int kc = 0; kc < 4; ++kc) {
                const int gr = ((4 * kc + qd) ^ ((4 * tb + (l15 >> 2)) & 7)) << 3;
                X[tb][kc] = *(const s8v*)&myxs[(tb * 16 + l15) * XSTR + gr];
            }

        const s8v* wf = (const s8v*)wpk;

        // --- v: D[t][o] = mfma(X, Wv) -> vt [hp][o=l15][t] in slot -> vf regs
        #pragma unroll
        for (int hp = 0; hp < 2; ++hp) {
            const int h = w4 + hp * 4;
            const int ob = 16 + h;
            s8v Wv[4];
            #pragma unroll
            for (int kc = 0; kc < 4; ++kc) Wv[kc] = wf[(ob * 4 + kc) * 64 + lane];
            short* vw = myv + hp * 16 * VSTR;
            const float vb = qkv_b[256 + h * 16 + l15];
            #pragma unroll
            for (int tb = 0; tb < 4; ++tb) {
                f4v acc = {0.f, 0.f, 0.f, 0.f};
                #pragma unroll
                for (int kc = 0; kc < 4; ++kc)
                    acc = __builtin_amdgcn_mfma_f32_16x16x32_bf16(X[tb][kc], Wv[kc], acc, 0, 0, 0);
                *(uint2*)&vw[l15 * VSTR + tb * 16 + qd * 4] =
                    pk4(acc[0] + vb, acc[1] + vb, acc[2] + vb, acc[3] + vb);
            }
            vf[hp][0] = *(const s8v*)&vw[l15 * VSTR + qd * 8];
            vf[hp][1] = *(const s8v*)&vw[l15 * VSTR + 32 + qd * 8];
        }

        // --- k: D[o][t] = mfma(Wk, X) -> k [hp][tok][ch-swizzled] (overwrites vt)
        #pragma unroll
        for (int hp = 0; hp < 2; ++hp) {
            const int h = w4 + hp * 4;
            const int ob = 8 + h;
            s8v Wk[4];
            #pragma unroll
            for (int kc = 0; kc < 4; ++kc) Wk[kc] = wf[(ob * 4 + kc) * 64 + lane];
            float4 kb = *(const float4*)&qkv_b[128 + h * 16 + qd * 4];
            #pragma unroll
            for (int tb = 0; tb < 4; ++tb) {
                f4v acc = {0.f, 0.f, 0.f, 0.f};
                #pragma unroll
                for (int kc = 0; kc < 4; ++kc)
                    acc = __builtin_amdgcn_mfma_f32_16x16x32_bf16(Wk[kc], X[tb][kc], acc, 0, 0, 0);
                // token = tb*16+l15, channels qd*4..+3 stored at granule qd^kswz
                *(uint2*)&myv[((hp * 64 + tb * 16 + l15) << 4) + ((qd ^ kswz) << 2)] =
                    pk4(acc[0] + kb.x, acc[1] + kb.y, acc[2] + kb.z, acc[3] + kb.w);
            }
        }

        // --- q: issue W loads BEFORE the barrier (latency overlaps the wait).
        s8v Wq[2][4];
        #pragma unroll
        for (int hp = 0; hp < 2; ++hp) {
            const int ob = w4 + hp * 4;
            #pragma unroll
            for (int kc = 0; kc < 4; ++kc) Wq[hp][kc] = wf[(ob * 4 + kc) * 64 + lane];
        }

        // Barrier protects xs from the q overlay below (all waves done with X).
        __syncthreads();

        #pragma unroll
        for (int hp = 0; hp < 2; ++hp) {
            const int h = w4 + hp * 4;
            float4 qb = *(const float4*)&qkv_b[h * 16 + qd * 4];
            const float qsc = 0.25f * LOG2E;
            #pragma unroll
            for (int tb = 0; tb < 4; ++tb) {
                f4v acc = {0.f, 0.f, 0.f, 0.f};
                #pragma unroll
                for (int kc = 0; kc < 4; ++kc)
                    acc = __builtin_amdgcn_mfma_f32_16x16x32_bf16(Wq[hp][kc], X[tb][kc], acc, 0, 0, 0);
                *(uint2*)&myxs[(tb * 16 + l15) * XSTR + h * 16 + qd * 4] =
                    pk4(acc[0] + qb.x * qsc, acc[1] + qb.y * qsc,
                        acc[2] + qb.z * qsc, acc[3] + qb.w * qsc);
            }
        }

        // kf load (k scratch still intact; P overwrites it only in stage 3)
        const s8v z8 = {};
        #pragma unroll
        for (int hp = 0; hp < 2; ++hp)
            #pragma unroll
            for (int nt = 0; nt < 4; ++nt) {
                s8v kr = *(const s8v*)&myv[((hp * 64 + nt * 16 + l15) << 4) +
                                           (((2 * (qd & 1)) ^ kswz) << 2)];
                kf[hp][nt] = (qd < 2) ? kr : z8;
            }
    }

    // ---------- Stage 3: attention, both head chains interleaved ----------
    // S^T[t_k][t_q] = mfma(k, q): lane holds 16 scores of ONE query (col=l15);
    // softmax = lane-local tree + 2 shfl across qd.
    short* os = myxs;   // attention-out overlays q slices head-by-head
    #pragma unroll
    for (int mq = 0; mq < 4; ++mq) {
        // bias prefetch first (global; hides under the MFMAs below)
        f4v bf[2][4];
        #pragma unroll
        for (int hp = 0; hp < 2; ++hp) {
            const int h = w4 + hp * 4;
            #pragma unroll
            for (int nt = 0; nt < 4; ++nt)
                bf[hp][nt] = *(const f4v*)&biasf[(size_t)(((h * 4 + mq) * 4 + nt) * 64 + lane) * 4];
        }
        s8v qf[2];
        #pragma unroll
        for (int hp = 0; hp < 2; ++hp) {
            const int h = w4 + hp * 4;
            qf[hp] = *(const s8v*)&myxs[(mq * 16 + l15) * XSTR + h * 16 + (qd & 1) * 8];
        }
        f4v sv[2][4];
        #pragma unroll
        for (int hp = 0; hp < 2; ++hp)
            #pragma unroll
            for (int nt = 0; nt < 4; ++nt) {
                f4v s = {0.f, 0.f, 0.f, 0.f};
                s = __builtin_amdgcn_mfma_f32_16x16x32_bf16(kf[hp][nt], qf[hp], s, 0, 0, 0);
                sv[hp][nt] = s + bf[hp][nt];   // scale+log2e folded into q/bias
            }
        // max (tree + 2 shfl), two chains
        float mx[2];
        #pragma unroll
        for (int hp = 0; hp < 2; ++hp) {
            f4v a01, a23, a;
            #pragma unroll
            for (int r = 0; r < 4; ++r) {
                a01[r] = fmaxf(sv[hp][0][r], sv[hp][1][r]);
                a23[r] = fmaxf(sv[hp][2][r], sv[hp][3][r]);
            }
            #pragma unroll
            for (int r = 0; r < 4; ++r) a[r] = fmaxf(a01[r], a23[r]);
            float m = fmaxf(fmaxf(a[0], a[1]), fmaxf(a[2], a[3]));
            m = fmaxf(m, __shfl_xor(m, 16, 64));
            m = fmaxf(m, __shfl_xor(m, 32, 64));
            mx[hp] = m;
        }
        // exp2 + tree-sum + 2 shfl, two chains
        float inv[2];
        #pragma unroll
        for (int hp = 0; hp < 2; ++hp) {
            #pragma unroll
            for (int nt = 0; nt < 4; ++nt)
                #pragma unroll
                for (int r = 0; r < 4; ++r)
                    sv[hp][nt][r] = exp2f(sv[hp][nt][r] - mx[hp]);
            f4v s01 = sv[hp][0] + sv[hp][1];
            f4v s23 = sv[hp][2] + sv[hp][3];
            f4v s4  = s01 + s23;
            float sm = (s4[0] + s4[1]) + (s4[2] + s4[3]);
            sm += __shfl_xor(sm, 16, 64);
            sm += __shfl_xor(sm, 32, 64);
            inv[hp] = 1.f / sm;
        }
        // normalized P -> per-(wave,hp) scratch (overwrites k; kf is in regs)
        #pragma unroll
        for (int hp = 0; hp < 2; ++hp) {
            const int h = w4 + hp * 4;
            short* pw = myv + hp * 16 * VSTR;
            #pragma unroll
            for (int nt = 0; nt < 4; ++nt)
                *(uint2*)&pw[l15 * VSTR + nt * 16 + qd * 4] =
                    pk4(sv[hp][nt][0] * inv[hp], sv[hp][nt][1] * inv[hp],
                        sv[hp][nt][2] * inv[hp], sv[hp][nt][3] * inv[hp]);
            s8v pa0 = *(const s8v*)&pw[l15 * VSTR + qd * 8];
            s8v pa1 = *(const s8v*)&pw[l15 * VSTR + 32 + qd * 8];
            f4v O = {0.f, 0.f, 0.f, 0.f};
            O = __builtin_amdgcn_mfma_f32_16x16x32_bf16(pa0, vf[hp][0], O, 0, 0, 0);
            O = __builtin_amdgcn_mfma_f32_16x16x32_bf16(pa1, vf[hp][1], O, 0, 0, 0);
            #pragma unroll
            for (int r = 0; r < 4; ++r)
                os[(mq * 16 + qd * 4 + r) * XSTR + h * HD + l15] = f2bf(O[r]);
        }
    }

    // ---------- Stage 4: prefetch proj frags BEFORE the barrier ----------
    const s8v* wf = (const s8v*)wpk;
    s8v B[2][4];
    float pb2[2]; int o2[2];
    #pragma unroll
    for (int nt = 0; nt < 2; ++nt) {
        const int ob = 24 + w4 * 2 + nt;
        o2[nt] = (w4 * 2 + nt) * 16 + l15;
        pb2[nt] = proj_b[o2[nt]];
        #pragma unroll
        for (int kc = 0; kc < 4; ++kc) B[nt][kc] = wf[(ob * 4 + kc) * 64 + lane];
    }
    __syncthreads();
    {
        s8v A[4][4];
        #pragma unroll
        for (int mt = 0; mt < 4; ++mt)
            #pragma unroll
            for (int kc = 0; kc < 4; ++kc)
                A[mt][kc] = *(const s8v*)&myxs[(mt * 16 + l15) * XSTR + kc * 32 + qd * 8];

        #pragma unroll
        for (int mt = 0; mt < 4; ++mt) {
            const int t0 = mt * 16 + qd * 4;
            const int pix = (h0 + (t0 >> 3)) * 256 + w0 + (t0 & 7);
            #pragma unroll
            for (int nt = 0; nt < 2; ++nt) {
                f4v acc = {0.f, 0.f, 0.f, 0.f};
                #pragma unroll
                for (int kc = 0; kc < 4; ++kc)
                    acc = __builtin_amdgcn_mfma_f32_16x16x32_bf16(A[mt][kc], B[nt][kc], acc, 0, 0, 0);
                float4 v = make_float4(acc[0] + pb2[nt], acc[1] + pb2[nt],
                                       acc[2] + pb2[nt], acc[3] + pb2[nt]);
                *(float4*)&out[((size_t)(b * CDIM + o2[nt])) * HW + pix] = v;
            }
        }
    }
}

extern "C" void kernel_launch(void* const* d_in, const int* in_sizes, int n_in,
                              void* d_out, int out_size, void* d_ws, size_t ws_size,
                              hipStream_t stream) {
    const float* x        = (const float*)d_in[0];
    const float* qkv_w    = (const float*)d_in[1];
    const float* qkv_b    = (const float*)d_in[2];
    const float* proj_w   = (const float*)d_in[3];
    const float* proj_b   = (const float*)d_in[4];
    const float* rel_bias = (const float*)d_in[5];
    const int*   rel_index= (const int*)d_in[6];
    float* out = (float*)d_out;

    short* wpk   = (short*)d_ws;                       // 32*4*64*8 shorts = 128 KB
    float* biasf = (float*)((char*)d_ws + 131072);     // 8192 float4 = 128 KB

    pack_w_kernel<<<32, 256, 0, stream>>>(qkv_w, proj_w, wpk);
    pack_b_kernel<<<32, 256, 0, stream>>>(rel_bias, rel_index, biasf);
    winattn_kernel<<<1024, 512, 0, stream>>>(x, qkv_b, proj_b, wpk, biasf, out);
}

// Round 5
// 181.641 us; speedup vs baseline: 1.0418x; 1.0418x over previous
//
#include <hip/hip_runtime.h>

#define CDIM 128
#define NHEADS 8
#define HD 16
#define NTOK 64
#define HW 65536          // 256*256 pixels per image
#define XSTR 136          // padded row stride (bf16 shorts) for 64x128 tiles
#define VSTR 72           // row stride (shorts) for [16][64] vt/P scratch tiles
#define SLOT 2304         // per-wave vsc slot (shorts) = max(2*64*16, 2*16*72)
#define LOG2E 1.44269504088896f

typedef short s8v __attribute__((ext_vector_type(8)));
typedef short s4v __attribute__((ext_vector_type(4)));
typedef float f4v __attribute__((ext_vector_type(4)));

static __device__ __forceinline__ short f2bf(float f) {
    unsigned u = __float_as_uint(f);
    u += 0x7FFFu + ((u >> 16) & 1u);   // RNE
    return (short)(u >> 16);
}
// packed RNE f32x2 -> bf16x2 (T12 recipe; no builtin on gfx950)
static __device__ __forceinline__ unsigned cvt2(float lo, float hi) {
    unsigned r;
    asm("v_cvt_pk_bf16_f32 %0, %1, %2" : "=v"(r) : "v"(lo), "v"(hi));
    return r;
}
static __device__ __forceinline__ uint2 pk4(float a, float b, float c, float d) {
    return make_uint2(cvt2(a, b), cvt2(c, d));
}

// ---- Prologue 1: pack qkv_w (rows 0..383) + proj_w (rows 0..127) into MFMA
// fragment order. frag f = ob*4+kc; ob 0..7 = q (pre-scaled 0.25*log2e so the
// softmax can use exp2 directly), 8..15 = k, 16..23 = v, 24..31 = proj.
// wpk[(f*64+lane)*8 + j] = W[ob*16 + (lane&15)][kc*32 + (lane>>4)*8 + j]
__global__ __launch_bounds__(256) void pack_w_kernel(
    const float* __restrict__ qkv_w, const float* __restrict__ proj_w,
    short* __restrict__ wpk)
{
    int idx = blockIdx.x * 256 + threadIdx.x;   // 0..8191
    int lane = idx & 63, kc = (idx >> 6) & 3, ob = idx >> 8;
    int row = (ob < 24) ? ob * 16 + (lane & 15) : (ob - 24) * 16 + (lane & 15);
    int col = kc * 32 + (lane >> 4) * 8;
    const float* src = ((ob < 24) ? qkv_w : proj_w) + (size_t)row * CDIM + col;
    float sc = (ob < 8) ? 0.25f * LOG2E : 1.0f;
    float4 f0 = *(const float4*)src;
    float4 f1 = *(const float4*)(src + 4);
    s8v r;
    r[0] = f2bf(f0.x * sc); r[1] = f2bf(f0.y * sc);
    r[2] = f2bf(f0.z * sc); r[3] = f2bf(f0.w * sc);
    r[4] = f2bf(f1.x * sc); r[5] = f2bf(f1.y * sc);
    r[6] = f2bf(f1.z * sc); r[7] = f2bf(f1.w * sc);
    *(s8v*)&wpk[(size_t)idx * 8] = r;
}

// ---- Prologue 2: gather rel_bias[rel_index] (scaled by log2e) into S^T
// C-fragment order: biasf[(((h*4+mq)*4+nt)*64 + lane)*4 + r] =
//   log2e * bias[h][t_q = mq*16+(lane&15)][t_k = nt*16+(lane>>4)*4+r]
__global__ __launch_bounds__(256) void pack_b_kernel(
    const float* __restrict__ rel_bias, const int* __restrict__ rel_index,
    float* __restrict__ biasf)
{
    int idx = blockIdx.x * 256 + threadIdx.x;   // 0..8191
    int lane = idx & 63, nt = (idx >> 6) & 3, mq = (idx >> 8) & 3, h = idx >> 10;
    int tq  = mq * 16 + (lane & 15);
    int tk0 = nt * 16 + (lane >> 4) * 4;
    f4v v;
    #pragma unroll
    for (int r = 0; r < 4; ++r)
        v[r] = LOG2E * rel_bias[rel_index[tq * 64 + tk0 + r] * NHEADS + h];
    *(f4v*)&biasf[(size_t)idx * 4] = v;
}

// ---- Main: one block per HORIZONTAL PAIR of 8x8 windows (8x16 px), 512
// threads = 8 waves. Waves 0-3 run window 0, waves 4-7 run window 1; wave
// quad-index w4 owns heads {w4, w4+4} of its window.
// XCD swizzle (bijective, 1024%8==0): consecutive LOGICAL pair-ids land on
// the same XCD, so the two pair-blocks sharing each 128B TCC line (32 px)
// execute on the same L2 nearly simultaneously -> half-line reads merge and
// half-written out lines coalesce before eviction.
__global__ __launch_bounds__(512, 4) void winattn_kernel(
    const float* __restrict__ x, const float* __restrict__ qkv_b,
    const float* __restrict__ proj_b, const short* __restrict__ wpk,
    const float* __restrict__ biasf, float* __restrict__ out)
{
    // per-window xs: staged x (granule-swizzled) -> q overlay -> attn-out
    __shared__ __align__(16) short xs[2 * NTOK * XSTR];   // 34816 B
    __shared__ __align__(16) short vsc[8 * SLOT];         // 36864 B (wave-private)

    const int tid  = threadIdx.x;
    const int lane = tid & 63;
    const int wv   = tid >> 6;       // 0..7
    const int win  = wv >> 2;        // window within the pair
    const int w4   = wv & 3;         // wave quad-index within the window
    const int qd   = lane >> 4;
    const int l15  = lane & 15;
    short* myxs = &xs[win * NTOK * XSTR];
    short* myv  = &vsc[wv * SLOT];

    // XCD swizzle: 1024 pair-blocks, 8 XCDs, 128 contiguous logical pairs
    // per XCD (8 window-rows) -> horizontal neighbors share an XCD L2.
    const int wid = (blockIdx.x & 7) * 128 + (blockIdx.x >> 3);
    const int b   = wid >> 9;
    const int rem = wid & 511;
    const int wy  = rem >> 4, kx = rem & 15;
    const int h0  = wy * 8, w0 = kx * 16 + win * 8;
    const float* xb = x + (size_t)b * CDIM * HW;

    // ---------- Stage 1: stage own window into myxs (bf16, granule-swizzled)
    // Element (t, c) lives at myxs[t*XSTR + (((c>>3) ^ ((t>>2)&7))<<3) + (c&7)].
    // T14 issue-early: all 8 global loads batched before the convert/write
    // chain so 8 HBM requests are in flight per thread.
    {
        float4 fr[8];
        int col8[8], t08[8];
        #pragma unroll
        for (int it = 0; it < 8; ++it) {
            const int g   = it * 4 + w4;              // 0..31 group id
            const int cg  = g & 15, tqg = g >> 4;
            const int c   = cg * 8 + ((lane >> 3) & 7);
            const int tq  = tqg * 8 + (lane & 7);
            const int t0  = tq * 4;
            fr[it] = *(const float4*)&xb[(size_t)c * HW + (h0 + (t0 >> 3)) * 256 + w0 + (t0 & 7)];
            col8[it] = ((cg ^ (tq & 7)) << 3) | (c & 7);
            t08[it]  = t0;
        }
        #pragma unroll
        for (int it = 0; it < 8; ++it) {
            const int t0 = t08[it], col = col8[it];
            myxs[(t0 + 0) * XSTR + col] = f2bf(fr[it].x);
            myxs[(t0 + 1) * XSTR + col] = f2bf(fr[it].y);
            myxs[(t0 + 2) * XSTR + col] = f2bf(fr[it].z);
            myxs[(t0 + 3) * XSTR + col] = f2bf(fr[it].w);
        }
    }
    __syncthreads();

    // ---------- Stage 2: QKV GEMM, head-aligned per wave; order v -> k -> q --
    s8v vf[2][2];   // v B-frags for heads {w4, w4+4}
    s8v kf[2][4];   // k A-frags (loaded after q-section)
    const int kswz = (l15 >> 1) & 2;   // even-only channel-granule XOR for k scratch
    {
        // X A-frags: X[tb][kc] = x[t = tb*16+l15][c = kc*32+qd*8 .. +7]
        s8v X[4][4];
        #pragma unroll
        for (int tb = 0; tb < 4; ++tb)
            #pragma unroll
            for (int kc = 0; kc < 4; ++kc) {
                const int gr = ((4 * kc + qd) ^ ((4 * tb + (l15 >> 2)) & 7)) << 3;
                X[tb][kc] = *(const s8v*)&myxs[(tb * 16 + l15) * XSTR + gr];
            }

        const s8v* wf = (const s8v*)wpk;

        // --- v: D[t][o] = mfma(X, Wv) -> vt [hp][o=l15][t] in slot -> vf regs
        #pragma unroll
        for (int hp = 0; hp < 2; ++hp) {
            const int h = w4 + hp * 4;
            const int ob = 16 + h;
            s8v Wv[4];
            #pragma unroll
            for (int kc = 0; kc < 4; ++kc) Wv[kc] = wf[(ob * 4 + kc) * 64 + lane];
            short* vw = myv + hp * 16 * VSTR;
            const float vb = qkv_b[256 + h * 16 + l15];
            #pragma unroll
            for (int tb = 0; tb < 4; ++tb) {
                f4v acc = {0.f, 0.f, 0.f, 0.f};
                #pragma unroll
                for (int kc = 0; kc < 4; ++kc)
                    acc = __builtin_amdgcn_mfma_f32_16x16x32_bf16(X[tb][kc], Wv[kc], acc, 0, 0, 0);
                *(uint2*)&vw[l15 * VSTR + tb * 16 + qd * 4] =
                    pk4(acc[0] + vb, acc[1] + vb, acc[2] + vb, acc[3] + vb);
            }
            vf[hp][0] = *(const s8v*)&vw[l15 * VSTR + qd * 8];
            vf[hp][1] = *(const s8v*)&vw[l15 * VSTR + 32 + qd * 8];
        }

        // --- k: D[o][t] = mfma(Wk, X) -> k [hp][tok][ch-swizzled] (overwrites vt)
        #pragma unroll
        for (int hp = 0; hp < 2; ++hp) {
            const int h = w4 + hp * 4;
            const int ob = 8 + h;
            s8v Wk[4];
            #pragma unroll
            for (int kc = 0; kc < 4; ++kc) Wk[kc] = wf[(ob * 4 + kc) * 64 + lane];
            float4 kb = *(const float4*)&qkv_b[128 + h * 16 + qd * 4];
            #pragma unroll
            for (int tb = 0; tb < 4; ++tb) {
                f4v acc = {0.f, 0.f, 0.f, 0.f};
                #pragma unroll
                for (int kc = 0; kc < 4; ++kc)
                    acc = __builtin_amdgcn_mfma_f32_16x16x32_bf16(Wk[kc], X[tb][kc], acc, 0, 0, 0);
                // token = tb*16+l15, channels qd*4..+3 stored at granule qd^kswz
                *(uint2*)&myv[((hp * 64 + tb * 16 + l15) << 4) + ((qd ^ kswz) << 2)] =
                    pk4(acc[0] + kb.x, acc[1] + kb.y, acc[2] + kb.z, acc[3] + kb.w);
            }
        }

        // --- q: issue W loads BEFORE the barrier (latency overlaps the wait).
        s8v Wq[2][4];
        #pragma unroll
        for (int hp = 0; hp < 2; ++hp) {
            const int ob = w4 + hp * 4;
            #pragma unroll
            for (int kc = 0; kc < 4; ++kc) Wq[hp][kc] = wf[(ob * 4 + kc) * 64 + lane];
        }

        // Barrier protects xs from the q overlay below (all waves done with X).
        __syncthreads();

        #pragma unroll
        for (int hp = 0; hp < 2; ++hp) {
            const int h = w4 + hp * 4;
            float4 qb = *(const float4*)&qkv_b[h * 16 + qd * 4];
            const float qsc = 0.25f * LOG2E;
            #pragma unroll
            for (int tb = 0; tb < 4; ++tb) {
                f4v acc = {0.f, 0.f, 0.f, 0.f};
                #pragma unroll
                for (int kc = 0; kc < 4; ++kc)
                    acc = __builtin_amdgcn_mfma_f32_16x16x32_bf16(Wq[hp][kc], X[tb][kc], acc, 0, 0, 0);
                *(uint2*)&myxs[(tb * 16 + l15) * XSTR + h * 16 + qd * 4] =
                    pk4(acc[0] + qb.x * qsc, acc[1] + qb.y * qsc,
                        acc[2] + qb.z * qsc, acc[3] + qb.w * qsc);
            }
        }

        // kf load (k scratch still intact; P overwrites it only in stage 3)
        const s8v z8 = {};
        #pragma unroll
        for (int hp = 0; hp < 2; ++hp)
            #pragma unroll
            for (int nt = 0; nt < 4; ++nt) {
                s8v kr = *(const s8v*)&myv[((hp * 64 + nt * 16 + l15) << 4) +
                                           (((2 * (qd & 1)) ^ kswz) << 2)];
                kf[hp][nt] = (qd < 2) ? kr : z8;
            }
    }

    // ---------- Stage 3: attention, both head chains interleaved ----------
    // S^T[t_k][t_q] = mfma(k, q): lane holds 16 scores of ONE query (col=l15);
    // softmax = lane-local tree + 2 shfl across qd.
    short* os = myxs;   // attention-out overlays q slices head-by-head
    #pragma unroll
    for (int mq = 0; mq < 4; ++mq) {
        // bias prefetch first (global; hides under the MFMAs below)
        f4v bf[2][4];
        #pragma unroll
        for (int hp = 0; hp < 2; ++hp) {
            const int h = w4 + hp * 4;
            #pragma unroll
            for (int nt = 0; nt < 4; ++nt)
                bf[hp][nt] = *(const f4v*)&biasf[(size_t)(((h * 4 + mq) * 4 + nt) * 64 + lane) * 4];
        }
        s8v qf[2];
        #pragma unroll
        for (int hp = 0; hp < 2; ++hp) {
            const int h = w4 + hp * 4;
            qf[hp] = *(const s8v*)&myxs[(mq * 16 + l15) * XSTR + h * 16 + (qd & 1) * 8];
        }
        f4v sv[2][4];
        #pragma unroll
        for (int hp = 0; hp < 2; ++hp)
            #pragma unroll
            for (int nt = 0; nt < 4; ++nt) {
                f4v s = {0.f, 0.f, 0.f, 0.f};
                s = __builtin_amdgcn_mfma_f32_16x16x32_bf16(kf[hp][nt], qf[hp], s, 0, 0, 0);
                sv[hp][nt] = s + bf[hp][nt];   // scale+log2e folded into q/bias
            }
        // max (tree + 2 shfl), two chains
        float mx[2];
        #pragma unroll
        for (int hp = 0; hp < 2; ++hp) {
            f4v a01, a23, a;
            #pragma unroll
            for (int r = 0; r < 4; ++r) {
                a01[r] = fmaxf(sv[hp][0][r], sv[hp][1][r]);
                a23[r] = fmaxf(sv[hp][2][r], sv[hp][3][r]);
            }
            #pragma unroll
            for (int r = 0; r < 4; ++r) a[r] = fmaxf(a01[r], a23[r]);
            float m = fmaxf(fmaxf(a[0], a[1]), fmaxf(a[2], a[3]));
            m = fmaxf(m, __shfl_xor(m, 16, 64));
            m = fmaxf(m, __shfl_xor(m, 32, 64));
            mx[hp] = m;
        }
        // exp2 + tree-sum + 2 shfl, two chains
        float inv[2];
        #pragma unroll
        for (int hp = 0; hp < 2; ++hp) {
            #pragma unroll
            for (int nt = 0; nt < 4; ++nt)
                #pragma unroll
                for (int r = 0; r < 4; ++r)
                    sv[hp][nt][r] = exp2f(sv[hp][nt][r] - mx[hp]);
            f4v s01 = sv[hp][0] + sv[hp][1];
            f4v s23 = sv[hp][2] + sv[hp][3];
            f4v s4  = s01 + s23;
            float sm = (s4[0] + s4[1]) + (s4[2] + s4[3]);
            sm += __shfl_xor(sm, 16, 64);
            sm += __shfl_xor(sm, 32, 64);
            inv[hp] = 1.f / sm;
        }
        // normalized P -> per-(wave,hp) scratch (overwrites k; kf is in regs)
        #pragma unroll
        for (int hp = 0; hp < 2; ++hp) {
            const int h = w4 + hp * 4;
            short* pw = myv + hp * 16 * VSTR;
            #pragma unroll
            for (int nt = 0; nt < 4; ++nt)
                *(uint2*)&pw[l15 * VSTR + nt * 16 + qd * 4] =
                    pk4(sv[hp][nt][0] * inv[hp], sv[hp][nt][1] * inv[hp],
                        sv[hp][nt][2] * inv[hp], sv[hp][nt][3] * inv[hp]);
            s8v pa0 = *(const s8v*)&pw[l15 * VSTR + qd * 8];
            s8v pa1 = *(const s8v*)&pw[l15 * VSTR + 32 + qd * 8];
            f4v O = {0.f, 0.f, 0.f, 0.f};
            O = __builtin_amdgcn_mfma_f32_16x16x32_bf16(pa0, vf[hp][0], O, 0, 0, 0);
            O = __builtin_amdgcn_mfma_f32_16x16x32_bf16(pa1, vf[hp][1], O, 0, 0, 0);
            #pragma unroll
            for (int r = 0; r < 4; ++r)
                os[(mq * 16 + qd * 4 + r) * XSTR + h * HD + l15] = f2bf(O[r]);
        }
    }

    // ---------- Stage 4: prefetch proj frags BEFORE the barrier ----------
    const s8v* wf = (const s8v*)wpk;
    s8v B[2][4];
    float pb2[2]; int o2[2];
    #pragma unroll
    for (int nt = 0; nt < 2; ++nt) {
        const int ob = 24 + w4 * 2 + nt;
        o2[nt] = (w4 * 2 + nt) * 16 + l15;
        pb2[nt] = proj_b[o2[nt]];
        #pragma unroll
        for (int kc = 0; kc < 4; ++kc) B[nt][kc] = wf[(ob * 4 + kc) * 64 + lane];
    }
    __syncthreads();
    {
        s8v A[4][4];
        #pragma unroll
        for (int mt = 0; mt < 4; ++mt)
            #pragma unroll
            for (int kc = 0; kc < 4; ++kc)
                A[mt][kc] = *(const s8v*)&myxs[(mt * 16 + l15) * XSTR + kc * 32 + qd * 8];

        #pragma unroll
        for (int mt = 0; mt < 4; ++mt) {
            const int t0 = mt * 16 + qd * 4;
            const int pix = (h0 + (t0 >> 3)) * 256 + w0 + (t0 & 7);
            #pragma unroll
            for (int nt = 0; nt < 2; ++nt) {
                f4v acc = {0.f, 0.f, 0.f, 0.f};
                #pragma unroll
                for (int kc = 0; kc < 4; ++kc)
                    acc = __builtin_amdgcn_mfma_f32_16x16x32_bf16(A[mt][kc], B[nt][kc], acc, 0, 0, 0);
                float4 v = make_float4(acc[0] + pb2[nt], acc[1] + pb2[nt],
                                       acc[2] + pb2[nt], acc[3] + pb2[nt]);
                *(float4*)&out[((size_t)(b * CDIM + o2[nt])) * HW + pix] = v;
            }
        }
    }
}

extern "C" void kernel_launch(void* const* d_in, const int* in_sizes, int n_in,
                              void* d_out, int out_size, void* d_ws, size_t ws_size,
                              hipStream_t stream) {
    const float* x        = (const float*)d_in[0];
    const float* qkv_w    = (const float*)d_in[1];
    const float* qkv_b    = (const float*)d_in[2];
    const float* proj_w   = (const float*)d_in[3];
    const float* proj_b   = (const float*)d_in[4];
    const float* rel_bias = (const float*)d_in[5];
    const int*   rel_index= (const int*)d_in[6];
    float* out = (float*)d_out;

    short* wpk   = (short*)d_ws;                       // 32*4*64*8 shorts = 128 KB
    float* biasf = (float*)((char*)d_ws + 131072);     // 8192 float4 = 128 KB

    pack_w_kernel<<<32, 256, 0, stream>>>(qkv_w, proj_w, wpk);
    pack_b_kernel<<<32, 256, 0, stream>>>(rel_bias, rel_index, biasf);
    winattn_kernel<<<1024, 512, 0, stream>>>(x, qkv_b, proj_b, wpk, biasf, out);
}

// Round 6
// 164.877 us; speedup vs baseline: 1.1477x; 1.1017x over previous
//
#include <hip/hip_runtime.h>

#define CDIM 128
#define NHEADS 8
#define HD 16
#define NTOK 64
#define HW 65536          // 256*256 pixels per image
#define XSTR 136          // padded row stride (bf16 shorts) for 64x128 tiles
#define VSTR 72           // row stride (shorts) for [16][64] vt/P scratch tiles
#define LOG2E 1.44269504088896f

typedef short s8v __attribute__((ext_vector_type(8)));
typedef short s4v __attribute__((ext_vector_type(4)));
typedef float f4v __attribute__((ext_vector_type(4)));

static __device__ __forceinline__ short f2bf(float f) {
    unsigned u = __float_as_uint(f);
    u += 0x7FFFu + ((u >> 16) & 1u);   // RNE
    return (short)(u >> 16);
}
// packed RNE f32x2 -> bf16x2 (T12 recipe; no builtin on gfx950)
static __device__ __forceinline__ unsigned cvt2(float lo, float hi) {
    unsigned r;
    asm("v_cvt_pk_bf16_f32 %0, %1, %2" : "=v"(r) : "v"(lo), "v"(hi));
    return r;
}
static __device__ __forceinline__ uint2 pk4(float a, float b, float c, float d) {
    return make_uint2(cvt2(a, b), cvt2(c, d));
}

// ---- Prologue (merged): blocks 0..31 pack weights, 32..63 pack bias.
// Weights: frag f = ob*4+kc; ob 0..7 = q (pre-scaled 0.25*log2e), 8..15 = k,
// 16..23 = v, 24..31 = proj.
//   wpk[(f*64+lane)*8 + j] = W[ob*16 + (lane&15)][kc*32 + (lane>>4)*8 + j]
// Bias (S^T C-frag order): biasf[(((h*4+mq)*4+nt)*64 + lane)*4 + r] =
//   log2e * bias[h][t_q = mq*16+(lane&15)][t_k = nt*16+(lane>>4)*4+r]
__global__ __launch_bounds__(256) void pack_kernel(
    const float* __restrict__ qkv_w, const float* __restrict__ proj_w,
    const float* __restrict__ rel_bias, const int* __restrict__ rel_index,
    short* __restrict__ wpk, float* __restrict__ biasf)
{
    if (blockIdx.x < 32) {
        int idx = blockIdx.x * 256 + threadIdx.x;   // 0..8191
        int lane = idx & 63, kc = (idx >> 6) & 3, ob = idx >> 8;
        int row = (ob < 24) ? ob * 16 + (lane & 15) : (ob - 24) * 16 + (lane & 15);
        int col = kc * 32 + (lane >> 4) * 8;
        const float* src = ((ob < 24) ? qkv_w : proj_w) + (size_t)row * CDIM + col;
        float sc = (ob < 8) ? 0.25f * LOG2E : 1.0f;
        float4 f0 = *(const float4*)src;
        float4 f1 = *(const float4*)(src + 4);
        s8v r;
        r[0] = f2bf(f0.x * sc); r[1] = f2bf(f0.y * sc);
        r[2] = f2bf(f0.z * sc); r[3] = f2bf(f0.w * sc);
        r[4] = f2bf(f1.x * sc); r[5] = f2bf(f1.y * sc);
        r[6] = f2bf(f1.z * sc); r[7] = f2bf(f1.w * sc);
        *(s8v*)&wpk[(size_t)idx * 8] = r;
    } else {
        int idx = (blockIdx.x - 32) * 256 + threadIdx.x;   // 0..8191
        int lane = idx & 63, nt = (idx >> 6) & 3, mq = (idx >> 8) & 3, h = idx >> 10;
        int tq  = mq * 16 + (lane & 15);
        int tk0 = nt * 16 + (lane >> 4) * 4;
        f4v v;
        #pragma unroll
        for (int r = 0; r < 4; ++r)
            v[r] = LOG2E * rel_bias[rel_index[tq * 64 + tk0 + r] * NHEADS + h];
        *(f4v*)&biasf[(size_t)idx * 4] = v;
    }
}

// ---- Main: one block per 8x8 window, 256 threads = 4 waves (R2 geometry:
// the measured traffic sweet spot — 3 blocks/CU, XCD swizzle x256 keeps
// neighboring windows on one XCD so half-line reads/writes merge in L2).
// Wave wv owns heads {wv, wv+4}: computes q/k/v for them and consumes them
// itself -> no barrier between QKV GEMM and attention.
__global__ __launch_bounds__(256, 3) void winattn_kernel(
    const float* __restrict__ x, const float* __restrict__ qkv_b,
    const float* __restrict__ proj_b, const short* __restrict__ wpk,
    const float* __restrict__ biasf, float* __restrict__ out)
{
    // xs: staged x (granule-swizzled) -> overlaid by q -> overlaid by attn-out
    __shared__ __align__(16) short xs[NTOK * XSTR];        // 17408 B
    __shared__ __align__(16) short ks[NTOK * XSTR];        // 17408 B (k [t][o])
    __shared__ __align__(16) short vsc[4 * 2 * 16 * VSTR]; // 18432 B scratch

    const int tid  = threadIdx.x;
    const int lane = tid & 63;
    const int wv   = tid >> 6;
    const int qd   = lane >> 4;
    const int l15  = lane & 15;

    // XCD swizzle: consecutive logical windows -> same XCD (L2 line sharing)
    const int wid = (blockIdx.x & 7) * 256 + (blockIdx.x >> 3);
    const int b   = wid >> 10;
    const int wy  = (wid >> 5) & 31, wx = wid & 31;
    const int h0  = wy * 8, w0 = wx * 8;
    const float* xb = x + (size_t)b * CDIM * HW;

    // ---------- Stage 1: stage x window into xs (bf16, granule-swizzled) ----
    // Element (t, c) lives at xs[t*XSTR + (((c>>3) ^ ((t>>2)&7))<<3) + (c&7)].
    // Lane roles: token-part in lane bits 0-2 -> wave reads contiguous 32B
    // global segments (coalesced). All 8 loads issued before the convert/write
    // chain (T14 issue-early) so 8 HBM requests are in flight per thread.
    {
        float4 fr[8];
        int col8[8], t08[8];
        #pragma unroll
        for (int it = 0; it < 8; ++it) {
            const int g   = it * 4 + wv;              // 0..31 group id
            const int cg  = g & 15, tqg = g >> 4;
            const int c   = cg * 8 + ((lane >> 3) & 7);
            const int tq  = tqg * 8 + (lane & 7);
            const int t0  = tq * 4;
            fr[it] = *(const float4*)&xb[(size_t)c * HW + (h0 + (t0 >> 3)) * 256 + w0 + (t0 & 7)];
            col8[it] = ((cg ^ (tq & 7)) << 3) | (c & 7);
            t08[it]  = t0;
        }
        #pragma unroll
        for (int it = 0; it < 8; ++it) {
            const int t0 = t08[it], col = col8[it];
            xs[(t0 + 0) * XSTR + col] = f2bf(fr[it].x);
            xs[(t0 + 1) * XSTR + col] = f2bf(fr[it].y);
            xs[(t0 + 2) * XSTR + col] = f2bf(fr[it].z);
            xs[(t0 + 3) * XSTR + col] = f2bf(fr[it].w);
        }
    }
    __syncthreads();

    // ---------- Stage 2: QKV GEMM, head-aligned per wave ----------
    s8v vf[2][2];   // v B-frags for heads {wv, wv+4}
    {
        // X A-frags: X[tb][kc] = x[t = tb*16+l15][c = kc*32+qd*8 .. +7]
        s8v X[4][4];
        #pragma unroll
        for (int tb = 0; tb < 4; ++tb)
            #pragma unroll
            for (int kc = 0; kc < 4; ++kc) {
                const int gr = ((4 * kc + qd) ^ ((4 * tb + (l15 >> 2)) & 7)) << 3;
                X[tb][kc] = *(const s8v*)&xs[(tb * 16 + l15) * XSTR + gr];
            }

        const s8v* wf = (const s8v*)wpk;

        // --- k for own heads: hoist W for both heads, then compute.
        {
            s8v Wk[2][4];
            #pragma unroll
            for (int hp = 0; hp < 2; ++hp) {
                const int ob = 8 + wv + hp * 4;
                #pragma unroll
                for (int kc = 0; kc < 4; ++kc) Wk[hp][kc] = wf[(ob * 4 + kc) * 64 + lane];
            }
            #pragma unroll
            for (int hp = 0; hp < 2; ++hp) {
                const int h = wv + hp * 4;
                float4 kb = *(const float4*)&qkv_b[128 + h * 16 + qd * 4];
                #pragma unroll
                for (int tb = 0; tb < 4; ++tb) {
                    f4v acc = {0.f, 0.f, 0.f, 0.f};
                    #pragma unroll
                    for (int kc = 0; kc < 4; ++kc)
                        acc = __builtin_amdgcn_mfma_f32_16x16x32_bf16(Wk[hp][kc], X[tb][kc], acc, 0, 0, 0);
                    *(uint2*)&ks[(tb * 16 + l15) * XSTR + h * 16 + qd * 4] =
                        pk4(acc[0] + kb.x, acc[1] + kb.y, acc[2] + kb.z, acc[3] + kb.w);
                }
            }
        }

        // --- v for own heads -> per-wave scratch [o][t] -> vf regs
        {
            s8v Wv[2][4];
            #pragma unroll
            for (int hp = 0; hp < 2; ++hp) {
                const int ob = 16 + wv + hp * 4;
                #pragma unroll
                for (int kc = 0; kc < 4; ++kc) Wv[hp][kc] = wf[(ob * 4 + kc) * 64 + lane];
            }
            #pragma unroll
            for (int hp = 0; hp < 2; ++hp) {
                const int h = wv + hp * 4;
                short* vw = &vsc[(wv * 2 + hp) * 16 * VSTR];
                const float vb = qkv_b[256 + h * 16 + l15];
                #pragma unroll
                for (int tb = 0; tb < 4; ++tb) {
                    f4v acc = {0.f, 0.f, 0.f, 0.f};
                    #pragma unroll
                    for (int kc = 0; kc < 4; ++kc)
                        acc = __builtin_amdgcn_mfma_f32_16x16x32_bf16(X[tb][kc], Wv[hp][kc], acc, 0, 0, 0);
                    *(uint2*)&vw[l15 * VSTR + tb * 16 + qd * 4] =
                        pk4(acc[0] + vb, acc[1] + vb, acc[2] + vb, acc[3] + vb);
                }
                vf[hp][0] = *(const s8v*)&vw[l15 * VSTR + qd * 8];
                vf[hp][1] = *(const s8v*)&vw[l15 * VSTR + 32 + qd * 8];
            }
        }

        // --- q: issue W loads BEFORE the barrier (latency overlaps the wait).
        s8v Wq[2][4];
        #pragma unroll
        for (int hp = 0; hp < 2; ++hp) {
            const int ob = wv + hp * 4;
            #pragma unroll
            for (int kc = 0; kc < 4; ++kc) Wq[hp][kc] = wf[(ob * 4 + kc) * 64 + lane];
        }

        // All waves must be done READING xs before q overlays it.
        __syncthreads();

        #pragma unroll
        for (int hp = 0; hp < 2; ++hp) {
            const int h = wv + hp * 4;
            float4 qb = *(const float4*)&qkv_b[h * 16 + qd * 4];
            const float qsc = 0.25f * LOG2E;
            #pragma unroll
            for (int tb = 0; tb < 4; ++tb) {
                f4v acc = {0.f, 0.f, 0.f, 0.f};
                #pragma unroll
                for (int kc = 0; kc < 4; ++kc)
                    acc = __builtin_amdgcn_mfma_f32_16x16x32_bf16(Wq[hp][kc], X[tb][kc], acc, 0, 0, 0);
                *(uint2*)&xs[(tb * 16 + l15) * XSTR + h * 16 + qd * 4] =
                    pk4(acc[0] + qb.x * qsc, acc[1] + qb.y * qsc,
                        acc[2] + qb.z * qsc, acc[3] + qb.w * qsc);
            }
        }
    }

    // ---------- Stage 3: attention, both head chains interleaved ----------
    // S^T[t_k][t_q] = mfma(k, q): lane holds 16 scores of ONE query (col=l15);
    // softmax = lane-local tree + 2 shfl across qd.
    short* os = xs;   // attention-out overlays q slices head-by-head
    const s8v z8 = {};
    s8v kf[2][4];     // A-frags: k[t_k = nt*16+l15][c]  (qd>=2 zeroed)
    #pragma unroll
    for (int hp = 0; hp < 2; ++hp) {
        const int h = wv + hp * 4;
        #pragma unroll
        for (int nt = 0; nt < 4; ++nt) {
            s8v kr = *(const s8v*)&ks[(nt * 16 + l15) * XSTR + h * 16 + (qd & 1) * 8];
            kf[hp][nt] = (qd < 2) ? kr : z8;
        }
    }
    #pragma unroll
    for (int mq = 0; mq < 4; ++mq) {
        // bias prefetch first (global; hides under the MFMAs below)
        f4v bf[2][4];
        #pragma unroll
        for (int hp = 0; hp < 2; ++hp) {
            const int h = wv + hp * 4;
            #pragma unroll
            for (int nt = 0; nt < 4; ++nt)
                bf[hp][nt] = *(const f4v*)&biasf[(size_t)(((h * 4 + mq) * 4 + nt) * 64 + lane) * 4];
        }
        s8v qf[2];
        #pragma unroll
        for (int hp = 0; hp < 2; ++hp) {
            const int h = wv + hp * 4;
            qf[hp] = *(const s8v*)&xs[(mq * 16 + l15) * XSTR + h * 16 + (qd & 1) * 8];
        }
        f4v sv[2][4];
        #pragma unroll
        for (int hp = 0; hp < 2; ++hp)
            #pragma unroll
            for (int nt = 0; nt < 4; ++nt) {
                f4v s = {0.f, 0.f, 0.f, 0.f};
                s = __builtin_amdgcn_mfma_f32_16x16x32_bf16(kf[hp][nt], qf[hp], s, 0, 0, 0);
                sv[hp][nt] = s + bf[hp][nt];   // scale+log2e folded into q/bias
            }
        // max (tree + 2 shfl), two chains
        float mx[2];
        #pragma unroll
        for (int hp = 0; hp < 2; ++hp) {
            f4v a01, a23, a;
            #pragma unroll
            for (int r = 0; r < 4; ++r) {
                a01[r] = fmaxf(sv[hp][0][r], sv[hp][1][r]);
                a23[r] = fmaxf(sv[hp][2][r], sv[hp][3][r]);
            }
            #pragma unroll
            for (int r = 0; r < 4; ++r) a[r] = fmaxf(a01[r], a23[r]);
            float m = fmaxf(fmaxf(a[0], a[1]), fmaxf(a[2], a[3]));
            m = fmaxf(m, __shfl_xor(m, 16, 64));
            m = fmaxf(m, __shfl_xor(m, 32, 64));
            mx[hp] = m;
        }
        // exp2 + tree-sum + 2 shfl, two chains
        float inv[2];
        #pragma unroll
        for (int hp = 0; hp < 2; ++hp) {
            #pragma unroll
            for (int nt = 0; nt < 4; ++nt)
                #pragma unroll
                for (int r = 0; r < 4; ++r)
                    sv[hp][nt][r] = exp2f(sv[hp][nt][r] - mx[hp]);
            f4v s01 = sv[hp][0] + sv[hp][1];
            f4v s23 = sv[hp][2] + sv[hp][3];
            f4v s4  = s01 + s23;
            float sm = (s4[0] + s4[1]) + (s4[2] + s4[3]);
            sm += __shfl_xor(sm, 16, 64);
            sm += __shfl_xor(sm, 32, 64);
            inv[hp] = 1.f / sm;
        }
        // normalized P -> per-(wave,hp) scratch (overwrites v-scratch; vf in regs)
        #pragma unroll
        for (int hp = 0; hp < 2; ++hp) {
            const int h = wv + hp * 4;
            short* pw = &vsc[(wv * 2 + hp) * 16 * VSTR];
            #pragma unroll
            for (int nt = 0; nt < 4; ++nt)
                *(uint2*)&pw[l15 * VSTR + nt * 16 + qd * 4] =
                    pk4(sv[hp][nt][0] * inv[hp], sv[hp][nt][1] * inv[hp],
                        sv[hp][nt][2] * inv[hp], sv[hp][nt][3] * inv[hp]);
            s8v pa0 = *(const s8v*)&pw[l15 * VSTR + qd * 8];
            s8v pa1 = *(const s8v*)&pw[l15 * VSTR + 32 + qd * 8];
            f4v O = {0.f, 0.f, 0.f, 0.f};
            O = __builtin_amdgcn_mfma_f32_16x16x32_bf16(pa0, vf[hp][0], O, 0, 0, 0);
            O = __builtin_amdgcn_mfma_f32_16x16x32_bf16(pa1, vf[hp][1], O, 0, 0, 0);
            #pragma unroll
            for (int r = 0; r < 4; ++r)
                os[(mq * 16 + qd * 4 + r) * XSTR + h * HD + l15] = f2bf(O[r]);
        }
    }

    // ---------- Stage 4: prefetch proj frags BEFORE the barrier ----------
    const s8v* wf = (const s8v*)wpk;
    s8v B[2][4];
    float pb2[2]; int o2[2];
    #pragma unroll
    for (int nt = 0; nt < 2; ++nt) {
        const int ob = 24 + wv * 2 + nt;
        o2[nt] = (wv * 2 + nt) * 16 + l15;
        pb2[nt] = proj_b[o2[nt]];
        #pragma unroll
        for (int kc = 0; kc < 4; ++kc) B[nt][kc] = wf[(ob * 4 + kc) * 64 + lane];
    }
    __syncthreads();
    {
        s8v A[4][4];
        #pragma unroll
        for (int mt = 0; mt < 4; ++mt)
            #pragma unroll
            for (int kc = 0; kc < 4; ++kc)
                A[mt][kc] = *(const s8v*)&xs[(mt * 16 + l15) * XSTR + kc * 32 + qd * 8];

        #pragma unroll
        for (int mt = 0; mt < 4; ++mt) {
            const int t0 = mt * 16 + qd * 4;
            const int pix = (h0 + (t0 >> 3)) * 256 + w0 + (t0 & 7);
            #pragma unroll
            for (int nt = 0; nt < 2; ++nt) {
                f4v acc = {0.f, 0.f, 0.f, 0.f};
                #pragma unroll
                for (int kc = 0; kc < 4; ++kc)
                    acc = __builtin_amdgcn_mfma_f32_16x16x32_bf16(A[mt][kc], B[nt][kc], acc, 0, 0, 0);
                float4 v = make_float4(acc[0] + pb2[nt], acc[1] + pb2[nt],
                                       acc[2] + pb2[nt], acc[3] + pb2[nt]);
                *(float4*)&out[((size_t)(b * CDIM + o2[nt])) * HW + pix] = v;
            }
        }
    }
}

extern "C" void kernel_launch(void* const* d_in, const int* in_sizes, int n_in,
                              void* d_out, int out_size, void* d_ws, size_t ws_size,
                              hipStream_t stream) {
    const float* x        = (const float*)d_in[0];
    const float* qkv_w    = (const float*)d_in[1];
    const float* qkv_b    = (const float*)d_in[2];
    const float* proj_w   = (const float*)d_in[3];
    const float* proj_b   = (const float*)d_in[4];
    const float* rel_bias = (const float*)d_in[5];
    const int*   rel_index= (const int*)d_in[6];
    float* out = (float*)d_out;

    short* wpk   = (short*)d_ws;                       // 32*4*64*8 shorts = 128 KB
    float* biasf = (float*)((char*)d_ws + 131072);     // 8192 float4 = 128 KB

    pack_kernel<<<64, 256, 0, stream>>>(qkv_w, proj_w, rel_bias, rel_index, wpk, biasf);
    winattn_kernel<<<2048, 256, 0, stream>>>(x, qkv_b, proj_b, wpk, biasf, out);
}